// Round 1
// 618.884 us; speedup vs baseline: 1.2883x; 1.2883x over previous
//
#include <hip/hip_runtime.h>

#define NBATCH 8
#define CH 64
#define HH 256
#define WW 256
#define CK 64          // w-chunk width
#define NCK (WW / CK)  // 4 chunks
#define LDP (CK + 4)   // 68-float row stride: keeps 16B alignment, 2-way banks only

// Algebraic refactor:
//   Aq = dwconv_q(hid) (incl. db), Ak = dwconv_k(ctx), Av = dwconv_v(ctx)
//   T  = Aq*Ak^T (64x64, reduced over w=256)   sq = Aq*1, sk = Ak*1
//   S  = SCALE*( qpw*T*kpw^T + (qpw*sq)*kpb^T + qpb*(kpw*sk)^T + 256*qpb*kpb^T )
//   P  = softmax_rows(S),  M = P*vpw,  pbd = P*vpb
//   O  = M*Av + pbd
// This removes all three 64x64x256 pointwise GEMMs (replaced by 64^3 projections),
// needs only TWO 64x68 LDS buffers -> 35.8 KB -> 4 blocks/CU (16 waves/CU).
__global__ __launch_bounds__(256, 4)
void fused_ca(const float* __restrict__ hid, const float* __restrict__ ctx,
              const float* __restrict__ qdw, const float* __restrict__ qdb,
              const float* __restrict__ qpw, const float* __restrict__ qpb,
              const float* __restrict__ kdw, const float* __restrict__ kdb,
              const float* __restrict__ kpw, const float* __restrict__ kpb,
              const float* __restrict__ vdw, const float* __restrict__ vdb,
              const float* __restrict__ vpw, const float* __restrict__ vpb,
              float* __restrict__ out)
{
    __shared__ float bufA[CH][LDP];   // 17408 B
    __shared__ float bufB[CH][LDP];   // 17408 B
    __shared__ float ssq[CH], ssk[CH], salpha[CH], sbeta[CH]; // 1024 B
                                      // total 35840 B -> 4 blocks/CU

    const int tid = threadIdx.x;
    // XCD-aware bijective swizzle: 2048 = 8 XCDs x 256. XCD x gets batch x,
    // h ascending -> 3-row depthwise overlap becomes an L2 hit per XCD.
    const int wg = (blockIdx.x & 7) * ((int)gridDim.x >> 3) + ((int)blockIdx.x >> 3);
    const int b  = wg >> 8;            // / HH
    const int h  = wg & 255;           // % HH

    const int r  = tid >> 2;           // row (channel / q-row) 0..63
    const int g  = tid & 3;
    const int c0 = g * 16;             // col base

    const float SCALE = 0.35355339059327373f; // 1/sqrt(HEAD_SIZE=8)

    // depthwise 3x3 conv for one 64-wide chunk; returns sum of the 16 outputs.
    // kmode=false: write bufA[r][c0+i] (row-major). kmode=true: write bufB[c0+i][r] (transposed).
    auto dwconv = [&](const float* __restrict__ src, const float* wgt, float bias,
                      int wc, bool kmode) -> float {
        float acc[16];
        #pragma unroll
        for (int i = 0; i < 16; i++) acc[i] = bias;
        const int w0 = wc * CK + c0 - 1;
        #pragma unroll
        for (int dy = 0; dy < 3; dy++) {
            const int hr = h + dy - 1;
            if (hr < 0 || hr >= HH) continue;            // uniform branch (h uniform)
            const float* p = src + (((size_t)b * CH + r) * HH + hr) * WW;
            float t[18];
            #pragma unroll
            for (int j = 0; j < 18; j++) {
                const int w = w0 + j;
                t[j] = (w >= 0 && w < WW) ? p[w] : 0.f;
            }
            #pragma unroll
            for (int dx = 0; dx < 3; dx++) {
                const float wv = wgt[dy * 3 + dx];
                #pragma unroll
                for (int i = 0; i < 16; i++) acc[i] += t[i + dx] * wv;
            }
        }
        float s = 0.f;
        #pragma unroll
        for (int i = 0; i < 16; i++) s += acc[i];
        if (kmode) {
            #pragma unroll
            for (int i = 0; i < 16; i++) bufB[c0 + i][r] = acc[i];
        } else {
            #pragma unroll
            for (int i = 0; i < 16; i++) bufA[r][c0 + i] = acc[i];
        }
        return s;
    };

    // ---- hoist q/k depthwise weights (L1 relief; 20 VGPRs) ----
    float qw[9], kw[9];
    #pragma unroll
    for (int i = 0; i < 9; i++) { qw[i] = qdw[r * 9 + i]; kw[i] = kdw[r * 9 + i]; }
    const float qb = qdb[r], kb = kdb[r];

    // ---- phase 1: T[r][c0..+15] += Aq[r][w]*Ak[d][w], accumulated in regs ----
    float sacc[16];
    #pragma unroll
    for (int i = 0; i < 16; i++) sacc[i] = 0.f;
    float sq_part = 0.f, sk_part = 0.f;

    for (int wc = 0; wc < NCK; wc++) {
        sq_part += dwconv(hid, qw, qb, wc, false);   // Aq chunk -> bufA[c][w]
        sk_part += dwconv(ctx, kw, kb, wc, true);    // Ak chunk -> bufB[w][d]
        __syncthreads();
        #pragma unroll 4
        for (int w = 0; w < CK; w++) {
            const float qv = bufA[r][w];
            #pragma unroll
            for (int i = 0; i < 16; i++) sacc[i] += qv * bufB[w][c0 + i];
        }
        __syncthreads();
    }

    // ---- row sums sq, sk (reduce the 4-lane group) ----
    sq_part += __shfl_xor(sq_part, 1);
    sq_part += __shfl_xor(sq_part, 2);
    sk_part += __shfl_xor(sk_part, 1);
    sk_part += __shfl_xor(sk_part, 2);
    if (g == 0) { ssq[r] = sq_part; ssk[r] = sk_part; }

    // ---- T -> bufA ----
    #pragma unroll
    for (int i = 0; i < 16; i++) bufA[r][c0 + i] = sacc[i];
    __syncthreads();

    // ---- W2 = SCALE * (qpw @ T) -> bufB ; alpha = qpw*sq, beta = kpw*sk ----
    {
        float acc[16];
        #pragma unroll
        for (int i = 0; i < 16; i++) acc[i] = 0.f;
        #pragma unroll 4
        for (int e = 0; e < CH; e++) {
            const float wv = qpw[r * CH + e];
            #pragma unroll
            for (int i = 0; i < 16; i++) acc[i] += wv * bufA[e][c0 + i];
        }
        #pragma unroll
        for (int i = 0; i < 16; i++) bufB[r][c0 + i] = acc[i] * SCALE;
    }
    if (tid < CH) {
        float a = 0.f;
        #pragma unroll 4
        for (int e = 0; e < CH; e++) a += qpw[tid * CH + e] * ssq[e];
        salpha[tid] = a;
    } else if (tid < 2 * CH) {
        const int d = tid - CH;
        float a = 0.f;
        #pragma unroll 4
        for (int e = 0; e < CH; e++) a += kpw[d * CH + e] * ssk[e];
        sbeta[d] = a;
    }
    __syncthreads();

    // ---- stage kpw^T -> bufA (T is consumed) ----
    #pragma unroll
    for (int j = 0; j < 4; j++) {
        const float4 kv = *reinterpret_cast<const float4*>(&kpw[r * CH + c0 + 4 * j]);
        bufA[c0 + 4 * j + 0][r] = kv.x;
        bufA[c0 + 4 * j + 1][r] = kv.y;
        bufA[c0 + 4 * j + 2][r] = kv.z;
        bufA[c0 + 4 * j + 3][r] = kv.w;
    }
    __syncthreads();

    // ---- S = W2 @ kpw^T + rank-1 bias terms ; softmax (in registers) ----
    float p[16];
    {
        float s[16];
        #pragma unroll
        for (int i = 0; i < 16; i++) s[i] = 0.f;
        #pragma unroll 4
        for (int e = 0; e < CH; e++) {
            const float wv = bufB[r][e];
            #pragma unroll
            for (int i = 0; i < 16; i++) s[i] += wv * bufA[e][c0 + i];
        }
        const float qpbr = qpb[r];
        const float gam  = SCALE * (salpha[r] + 256.f * qpbr);
        const float qs   = SCALE * qpbr;
        #pragma unroll
        for (int i = 0; i < 16; i++)
            s[i] += gam * kpb[c0 + i] + qs * sbeta[c0 + i];
        // softmax over the 64-wide row held by the 4-lane group
        float m = s[0];
        #pragma unroll
        for (int i = 1; i < 16; i++) m = fmaxf(m, s[i]);
        m = fmaxf(m, __shfl_xor(m, 1));
        m = fmaxf(m, __shfl_xor(m, 2));
        float sum = 0.f;
        #pragma unroll
        for (int i = 0; i < 16; i++) { s[i] = __expf(s[i] - m); sum += s[i]; }
        sum += __shfl_xor(sum, 1);
        sum += __shfl_xor(sum, 2);
        const float inv = 1.f / sum;
        #pragma unroll
        for (int i = 0; i < 16; i++) p[i] = s[i] * inv;
    }
    __syncthreads();

    // ---- P -> bufA ; stage vpw -> bufB (W2 consumed) ----
    #pragma unroll
    for (int i = 0; i < 16; i++) bufA[r][c0 + i] = p[i];
    #pragma unroll
    for (int j = 0; j < 4; j++) {
        *reinterpret_cast<float4*>(&bufB[r][c0 + 4 * j]) =
            *reinterpret_cast<const float4*>(&vpw[r * CH + c0 + 4 * j]);
    }
    __syncthreads();

    // ---- M = P @ vpw -> regs ; pbd = P . vpb ----
    float macc[16];
    #pragma unroll
    for (int i = 0; i < 16; i++) macc[i] = 0.f;
    float pbd = 0.f;
    #pragma unroll 4
    for (int d = 0; d < CH; d++) {
        const float pv = bufA[r][d];
        pbd += pv * vpb[d];
        #pragma unroll
        for (int i = 0; i < 16; i++) macc[i] += pv * bufB[d][c0 + i];
    }
    __syncthreads();
    #pragma unroll
    for (int i = 0; i < 16; i++) bufB[r][c0 + i] = macc[i];   // M (over vpw)

    float vw[9];
    #pragma unroll
    for (int i = 0; i < 9; i++) vw[i] = vdw[r * 9 + i];
    const float vb = vdb[r];
    __syncthreads();

    // ---- phase 2: O = M @ Av + pbd, chunk by chunk ----
    for (int wc = 0; wc < NCK; wc++) {
        (void)dwconv(ctx, vw, vb, wc, false);    // Av chunk -> bufA[e][w]
        __syncthreads();
        float o[16];
        #pragma unroll
        for (int i = 0; i < 16; i++) o[i] = 0.f;
        #pragma unroll 4
        for (int e = 0; e < CH; e++) {
            const float mv = bufB[r][e];
            #pragma unroll
            for (int i = 0; i < 16; i++) o[i] += mv * bufA[e][c0 + i];
        }
        float* po = out + (((size_t)b * CH + r) * HH + h) * WW + wc * CK + c0;
        #pragma unroll
        for (int i = 0; i < 16; i++) po[i] = o[i] + pbd;
        __syncthreads();
    }
}

extern "C" void kernel_launch(void* const* d_in, const int* in_sizes, int n_in,
                              void* d_out, int out_size, void* d_ws, size_t ws_size,
                              hipStream_t stream) {
    const float* hid = (const float*)d_in[0];
    const float* ctx = (const float*)d_in[1];
    const float* qdw = (const float*)d_in[2];
    const float* qdb = (const float*)d_in[3];
    const float* qpw = (const float*)d_in[4];
    const float* qpb = (const float*)d_in[5];
    const float* kdw = (const float*)d_in[6];
    const float* kdb = (const float*)d_in[7];
    const float* kpw = (const float*)d_in[8];
    const float* kpb = (const float*)d_in[9];
    const float* vdw = (const float*)d_in[10];
    const float* vdb = (const float*)d_in[11];
    const float* vpw = (const float*)d_in[12];
    const float* vpb = (const float*)d_in[13];
    float* out = (float*)d_out;

    dim3 grid(NBATCH * HH);   // 2048 blocks, one per (b, h)
    dim3 block(256);
    fused_ca<<<grid, block, 0, stream>>>(hid, ctx, qdw, qdb, qpw, qpb,
                                         kdw, kdb, kpw, kpb, vdw, vdb, vpw, vpb,
                                         out);
}

// Round 2
// 585.834 us; speedup vs baseline: 1.3610x; 1.0564x over previous
//
#include <hip/hip_runtime.h>

#define NBATCH 8
#define CH 64
#define HH 256
#define WW 256
#define CK 64          // w-chunk width
#define NCK (WW / CK)  // 4 chunks
#define LDP (CK + 4)   // 68-float row stride: 16B-aligned rows, 2-way banks only

// Algebra (verified round 1):
//   Aq = dwconv_q(hid), Ak = dwconv_k(ctx), Av = dwconv_v(ctx)   (incl. depthwise bias)
//   T  = Aq*Ak^T (64x64 over w=256),  sq = Aq*1, sk = Ak*1
//   S  = SCALE*( qpw*T*kpw^T + (qpw*sq)*kpb^T + qpb*(kpw*sk)^T + 256*qpb*kpb^T )
//   P  = softmax_rows(S),  M = P*vpw,  pbd = P*vpb,  O = M*Av + pbd
// launch_bounds(256,2): round-0-proven no-spill setting (92 VGPR). LDS 35840 B
// independently gives 4 blocks/CU = 16 waves/CU; VGPR budget 256 so RA won't spill.
__global__ __launch_bounds__(256, 2)
void fused_ca(const float* __restrict__ hid, const float* __restrict__ ctx,
              const float* __restrict__ qdw, const float* __restrict__ qdb,
              const float* __restrict__ qpw, const float* __restrict__ qpb,
              const float* __restrict__ kdw, const float* __restrict__ kdb,
              const float* __restrict__ kpw, const float* __restrict__ kpb,
              const float* __restrict__ vdw, const float* __restrict__ vdb,
              const float* __restrict__ vpw, const float* __restrict__ vpb,
              float* __restrict__ out)
{
    __shared__ float bufA[CH][LDP];   // 17408 B
    __shared__ float bufB[CH][LDP];   // 17408 B
    __shared__ float ssq[CH], ssk[CH], salpha[CH], sbeta[CH]; // 1024 B
                                      // total 35840 B -> 4 blocks/CU

    const int tid = threadIdx.x;
    // XCD-aware bijective swizzle (2048 = 8 XCDs x 256): each XCD sees one batch,
    // ascending h -> depthwise 3-row overlap is an L2 hit.
    const int wg = (blockIdx.x & 7) * ((int)gridDim.x >> 3) + ((int)blockIdx.x >> 3);
    const int b  = wg >> 8;
    const int h  = wg & 255;

    const int r  = tid >> 2;           // row (channel / q-row) 0..63
    const int g  = tid & 3;
    const int c0 = g * 16;             // col base

    const float SCALE = 0.35355339059327373f; // 1/sqrt(HEAD_SIZE=8)

    // depthwise 3x3 conv for a 16-wide strip; returns sum of the 16 outputs.
    // Loads: 4x float4 interior + 2 clamped edge scalars per row (no per-elem guards).
    auto dwconv = [&](const float* __restrict__ src, const float* wgt, float bias,
                      int wc, bool kmode) -> float {
        float acc[16];
        #pragma unroll
        for (int i = 0; i < 16; i++) acc[i] = bias;
        const int wb = wc * CK + c0;                 // first interior tap, mult of 16
        const float* p0 = src + ((size_t)b * CH + r) * HH * WW + wb;
        const int offL = (wb > 0) ? -1 : 0;          // clamped, always in-bounds
        const int offR = (wb + 16 < WW) ? 16 : 15;
        #pragma unroll
        for (int dy = 0; dy < 3; dy++) {
            const int hr = h + dy - 1;
            if (hr < 0 || hr >= HH) continue;        // uniform branch (h uniform)
            const float* p = p0 + (size_t)hr * WW;
            const float4 t0 = *reinterpret_cast<const float4*>(p);
            const float4 t1 = *reinterpret_cast<const float4*>(p + 4);
            const float4 t2 = *reinterpret_cast<const float4*>(p + 8);
            const float4 t3 = *reinterpret_cast<const float4*>(p + 12);
            float tl = p[offL]; if (wb == 0) tl = 0.f;
            float tr = p[offR]; if (wb + 16 >= WW) tr = 0.f;
            const float t[18] = {tl, t0.x, t0.y, t0.z, t0.w, t1.x, t1.y, t1.z, t1.w,
                                 t2.x, t2.y, t2.z, t2.w, t3.x, t3.y, t3.z, t3.w, tr};
            #pragma unroll
            for (int dx = 0; dx < 3; dx++) {
                const float wv = wgt[dy * 3 + dx];
                #pragma unroll
                for (int i = 0; i < 16; i++) acc[i] += t[i + dx] * wv;
            }
        }
        float s = 0.f;
        #pragma unroll
        for (int i = 0; i < 16; i++) s += acc[i];
        if (kmode) {
            #pragma unroll
            for (int i = 0; i < 16; i++) bufB[c0 + i][r] = acc[i];
        } else {
            #pragma unroll
            for (int j = 0; j < 4; j++)
                *reinterpret_cast<float4*>(&bufA[r][c0 + 4 * j]) =
                    make_float4(acc[4 * j], acc[4 * j + 1], acc[4 * j + 2], acc[4 * j + 3]);
        }
        return s;
    };

    // ---- hoist q/k depthwise weights ----
    float qw[9], kw[9];
    #pragma unroll
    for (int i = 0; i < 9; i++) { qw[i] = qdw[r * 9 + i]; kw[i] = kdw[r * 9 + i]; }
    const float qb = qdb[r], kb = kdb[r];

    // ---- phase 1: T[r][c0..+15] += Aq[r][w]*Ak[d][w] over 4 chunks ----
    float sacc[16];
    #pragma unroll
    for (int i = 0; i < 16; i++) sacc[i] = 0.f;
    float sq_part = 0.f, sk_part = 0.f;

    for (int wc = 0; wc < NCK; wc++) {
        sq_part += dwconv(hid, qw, qb, wc, false);   // Aq chunk -> bufA[c][w]
        sk_part += dwconv(ctx, kw, kb, wc, true);    // Ak chunk -> bufB[w][d]
        __syncthreads();
        #pragma unroll 2
        for (int w = 0; w < CK; w += 4) {
            const float4 qv = *reinterpret_cast<const float4*>(&bufA[r][w]);
            const float qs[4] = {qv.x, qv.y, qv.z, qv.w};
            #pragma unroll
            for (int j = 0; j < 4; j++)
                #pragma unroll
                for (int i = 0; i < 16; i++)
                    sacc[i] += qs[j] * bufB[w + j][c0 + i];
        }
        __syncthreads();
    }

    // ---- row sums sq, sk ----
    sq_part += __shfl_xor(sq_part, 1);
    sq_part += __shfl_xor(sq_part, 2);
    sk_part += __shfl_xor(sk_part, 1);
    sk_part += __shfl_xor(sk_part, 2);
    if (g == 0) { ssq[r] = sq_part; ssk[r] = sk_part; }

    // ---- T -> bufA ----
    #pragma unroll
    for (int j = 0; j < 4; j++)
        *reinterpret_cast<float4*>(&bufA[r][c0 + 4 * j]) =
            make_float4(sacc[4 * j], sacc[4 * j + 1], sacc[4 * j + 2], sacc[4 * j + 3]);
    __syncthreads();

    // ---- W2 = SCALE*(qpw @ T) -> bufB ; alpha = qpw*sq, beta = kpw*sk ----
    {
        float acc[16];
        #pragma unroll
        for (int i = 0; i < 16; i++) acc[i] = 0.f;
        #pragma unroll 2
        for (int e = 0; e < CH; e += 4) {
            const float4 wv4 = *reinterpret_cast<const float4*>(&qpw[r * CH + e]);
            const float ws[4] = {wv4.x, wv4.y, wv4.z, wv4.w};
            #pragma unroll
            for (int j = 0; j < 4; j++)
                #pragma unroll
                for (int i = 0; i < 16; i++)
                    acc[i] += ws[j] * bufA[e + j][c0 + i];
        }
        #pragma unroll
        for (int j = 0; j < 4; j++)
            *reinterpret_cast<float4*>(&bufB[r][c0 + 4 * j]) =
                make_float4(acc[4 * j] * SCALE, acc[4 * j + 1] * SCALE,
                            acc[4 * j + 2] * SCALE, acc[4 * j + 3] * SCALE);
    }
    if (tid < CH) {
        float a = 0.f;
        #pragma unroll 4
        for (int e = 0; e < CH; e += 4) {
            const float4 wv4 = *reinterpret_cast<const float4*>(&qpw[tid * CH + e]);
            a += wv4.x * ssq[e] + wv4.y * ssq[e + 1] + wv4.z * ssq[e + 2] + wv4.w * ssq[e + 3];
        }
        salpha[tid] = a;
    } else if (tid < 2 * CH) {
        const int d = tid - CH;
        float a = 0.f;
        #pragma unroll 4
        for (int e = 0; e < CH; e += 4) {
            const float4 wv4 = *reinterpret_cast<const float4*>(&kpw[d * CH + e]);
            a += wv4.x * ssk[e] + wv4.y * ssk[e + 1] + wv4.z * ssk[e + 2] + wv4.w * ssk[e + 3];
        }
        sbeta[d] = a;
    }
    __syncthreads();

    // ---- stage kpw^T -> bufA (T consumed) ----
    #pragma unroll
    for (int j = 0; j < 4; j++) {
        const float4 kv = *reinterpret_cast<const float4*>(&kpw[r * CH + c0 + 4 * j]);
        bufA[c0 + 4 * j + 0][r] = kv.x;
        bufA[c0 + 4 * j + 1][r] = kv.y;
        bufA[c0 + 4 * j + 2][r] = kv.z;
        bufA[c0 + 4 * j + 3][r] = kv.w;
    }
    __syncthreads();

    // ---- S = W2 @ kpw^T + rank-1 terms ; softmax in registers ----
    float p[16];
    {
        float s[16];
        #pragma unroll
        for (int i = 0; i < 16; i++) s[i] = 0.f;
        #pragma unroll 2
        for (int e = 0; e < CH; e += 4) {
            const float4 wv4 = *reinterpret_cast<const float4*>(&bufB[r][e]);
            const float ws[4] = {wv4.x, wv4.y, wv4.z, wv4.w};
            #pragma unroll
            for (int j = 0; j < 4; j++)
                #pragma unroll
                for (int i = 0; i < 16; i++)
                    s[i] += ws[j] * bufA[e + j][c0 + i];
        }
        const float qpbr = qpb[r];
        const float gam  = SCALE * (salpha[r] + 256.f * qpbr);
        const float qs   = SCALE * qpbr;
        #pragma unroll
        for (int i = 0; i < 16; i++)
            s[i] += gam * kpb[c0 + i] + qs * sbeta[c0 + i];
        float m = s[0];
        #pragma unroll
        for (int i = 1; i < 16; i++) m = fmaxf(m, s[i]);
        m = fmaxf(m, __shfl_xor(m, 1));
        m = fmaxf(m, __shfl_xor(m, 2));
        float sum = 0.f;
        #pragma unroll
        for (int i = 0; i < 16; i++) { s[i] = __expf(s[i] - m); sum += s[i]; }
        sum += __shfl_xor(sum, 1);
        sum += __shfl_xor(sum, 2);
        const float inv = 1.f / sum;
        #pragma unroll
        for (int i = 0; i < 16; i++) p[i] = s[i] * inv;
    }
    __syncthreads();

    // ---- P -> bufA ; vpw -> bufB ----
    #pragma unroll
    for (int j = 0; j < 4; j++)
        *reinterpret_cast<float4*>(&bufA[r][c0 + 4 * j]) =
            make_float4(p[4 * j], p[4 * j + 1], p[4 * j + 2], p[4 * j + 3]);
    #pragma unroll
    for (int j = 0; j < 4; j++)
        *reinterpret_cast<float4*>(&bufB[r][c0 + 4 * j]) =
            *reinterpret_cast<const float4*>(&vpw[r * CH + c0 + 4 * j]);
    __syncthreads();

    // ---- M = P @ vpw ; pbd = P . vpb ----
    float macc[16];
    #pragma unroll
    for (int i = 0; i < 16; i++) macc[i] = 0.f;
    float pbd = 0.f;
    #pragma unroll 2
    for (int d = 0; d < CH; d += 4) {
        const float4 pv4 = *reinterpret_cast<const float4*>(&bufA[r][d]);
        const float4 vb4 = *reinterpret_cast<const float4*>(&vpb[d]);
        pbd += pv4.x * vb4.x + pv4.y * vb4.y + pv4.z * vb4.z + pv4.w * vb4.w;
        const float ps[4] = {pv4.x, pv4.y, pv4.z, pv4.w};
        #pragma unroll
        for (int j = 0; j < 4; j++)
            #pragma unroll
            for (int i = 0; i < 16; i++)
                macc[i] += ps[j] * bufB[d + j][c0 + i];
    }
    __syncthreads();
    #pragma unroll
    for (int j = 0; j < 4; j++)
        *reinterpret_cast<float4*>(&bufB[r][c0 + 4 * j]) =
            make_float4(macc[4 * j], macc[4 * j + 1], macc[4 * j + 2], macc[4 * j + 3]);

    float vw[9];
    #pragma unroll
    for (int i = 0; i < 9; i++) vw[i] = vdw[r * 9 + i];
    const float vb = vdb[r];
    __syncthreads();

    // ---- phase 2: O = M @ Av + pbd, chunk by chunk ----
    for (int wc = 0; wc < NCK; wc++) {
        (void)dwconv(ctx, vw, vb, wc, false);        // Av chunk -> bufA[e][w]
        __syncthreads();
        float o[16];
        #pragma unroll
        for (int i = 0; i < 16; i++) o[i] = 0.f;
        #pragma unroll 2
        for (int e = 0; e < CH; e += 4) {
            const float4 mv4 = *reinterpret_cast<const float4*>(&bufB[r][e]);
            const float ms[4] = {mv4.x, mv4.y, mv4.z, mv4.w};
            #pragma unroll
            for (int j = 0; j < 4; j++)
                #pragma unroll
                for (int i = 0; i < 16; i++)
                    o[i] += ms[j] * bufA[e + j][c0 + i];
        }
        float* po = out + (((size_t)b * CH + r) * HH + h) * WW + wc * CK + c0;
        #pragma unroll
        for (int j = 0; j < 4; j++)
            *reinterpret_cast<float4*>(po + 4 * j) =
                make_float4(o[4 * j] + pbd, o[4 * j + 1] + pbd,
                            o[4 * j + 2] + pbd, o[4 * j + 3] + pbd);
        __syncthreads();
    }
}

extern "C" void kernel_launch(void* const* d_in, const int* in_sizes, int n_in,
                              void* d_out, int out_size, void* d_ws, size_t ws_size,
                              hipStream_t stream) {
    const float* hid = (const float*)d_in[0];
    const float* ctx = (const float*)d_in[1];
    const float* qdw = (const float*)d_in[2];
    const float* qdb = (const float*)d_in[3];
    const float* qpw = (const float*)d_in[4];
    const float* qpb = (const float*)d_in[5];
    const float* kdw = (const float*)d_in[6];
    const float* kdb = (const float*)d_in[7];
    const float* kpw = (const float*)d_in[8];
    const float* kpb = (const float*)d_in[9];
    const float* vdw = (const float*)d_in[10];
    const float* vdb = (const float*)d_in[11];
    const float* vpw = (const float*)d_in[12];
    const float* vpb = (const float*)d_in[13];
    float* out = (float*)d_out;

    dim3 grid(NBATCH * HH);   // 2048 blocks, one per (b, h)
    dim3 block(256);
    fused_ca<<<grid, block, 0, stream>>>(hid, ctx, qdw, qdb, qpw, qpb,
                                         kdw, kdb, kpw, kpb, vdw, vdb, vpw, vpb,
                                         out);
}